// Round 2
// baseline (255.343 us; speedup 1.0000x reference)
//
#include <hip/hip_runtime.h>

#define NIN 64
#define NOUT 32
#define TBITS 21                 // 128^3 stride-2 lattice
#define TSIZE (1 << TBITS)
#define NB 4096                  // buckets: 512 spatial cells (32^3) x 8 parity classes

typedef __attribute__((ext_vector_type(8))) short short8;
typedef __attribute__((ext_vector_type(4))) float float4v;
typedef __attribute__((ext_vector_type(4))) unsigned short ushort4v;

__device__ __forceinline__ unsigned short bf16rne(float x) {
    unsigned u = __float_as_uint(x);
    u += 0x7fffu + ((u >> 16) & 1u);
    return (unsigned short)(u >> 16);
}

__device__ __forceinline__ int bucket_of(int4 q, int* cls) {
    int c = (q.y & 1) | ((q.z & 1) << 1) | ((q.w & 1) << 2);
    *cls = c;
    // spatial-major: all 8 classes of one 32^3 cell are adjacent in bucket order
    int sp = ((((q.w & 255) >> 5) << 3 | ((q.z & 255) >> 5)) << 3) | ((q.y & 255) >> 5);
    return (sp << 3) | c;
}

// ws (ints): [0,TSIZE) table | [TSIZE, TSIZE+2*SC) sorted int2 (-1 padded) |
//   A=TSIZE+2*SC: count[NB] | cursor[NB] at A+NB | total[4] at A+2NB |
//   wt bf16 [27][32][64] at A+2NB+4 | fb bf16 [Np][64] after wt
// prep: init table+sorted to -1, zero count, wcvt, fcvt (all independent)
__global__ void prep(int4* __restrict__ ws4, int n4,
                     int4* __restrict__ count4,
                     const float* __restrict__ w, unsigned short* __restrict__ wt,
                     const float* __restrict__ f, unsigned short* __restrict__ fb,
                     int fn4) {
    int i = blockIdx.x * blockDim.x + threadIdx.x;
    if (i < n4) ws4[i] = make_int4(-1, -1, -1, -1);
    if (i < NB / 4) count4[i] = make_int4(0, 0, 0, 0);
    if (i < 27 * 64 * 32) {          // fp32 [27][64][32] -> bf16 [27][32][64]
        int oi = i >> 11;
        int k  = (i >> 5) & 63;
        int ch = i & 31;
        wt[oi * 2048 + ch * 64 + k] = bf16rne(w[i]);
    }
    if (i < fn4) {                   // fp32 feats -> bf16 mirror, 4/thread
        float4 v = ((const float4*)f)[i];
        ushort4v o;
        o.x = bf16rne(v.x); o.y = bf16rne(v.y);
        o.z = bf16rne(v.z); o.w = bf16rne(v.w);
        ((ushort4v*)fb)[i] = o;
    }
}

// build hash table (needs table init) + count bucket sizes (independent)
__global__ void bc(const int* __restrict__ coords, int np, int* __restrict__ table,
                   const int* __restrict__ guide, int ng, int* __restrict__ count) {
    int i = blockIdx.x * blockDim.x + threadIdx.x;
    if (i < np) {
        int x = coords[i * 4 + 1];
        int y = coords[i * 4 + 2];
        int z = coords[i * 4 + 3];
        table[(x >> 1) | ((y >> 1) << 7) | ((z >> 1) << 14)] = i;
    }
    if (i < ng) {
        int c;
        int b = bucket_of(((const int4*)guide)[i], &c);
        atomicAdd(&count[b], 1);
    }
}

// exclusive scan of 16-padded bucket sizes; one block of 1024, 4 buckets/thread
__global__ void scanB(const int* __restrict__ count, int* __restrict__ cursor,
                      int* __restrict__ total) {
    __shared__ int ps[1024];
    int t = threadIdx.x;
    int4 c4 = ((const int4*)count)[t];
    int p0 = (c4.x + 15) & ~15, p1 = (c4.y + 15) & ~15;
    int p2 = (c4.z + 15) & ~15, p3 = (c4.w + 15) & ~15;
    ps[t] = p0 + p1 + p2 + p3;
    __syncthreads();
    for (int off = 1; off < 1024; off <<= 1) {
        int v = ps[t];
        int u = (t >= off) ? ps[t - off] : 0;
        __syncthreads();
        ps[t] = v + u;
        __syncthreads();
    }
    int excl = (t == 0) ? 0 : ps[t - 1];
    int4 o;
    o.x = excl; o.y = excl + p0; o.z = excl + p0 + p1; o.w = excl + p0 + p1 + p2;
    ((int4*)cursor)[t] = o;
    if (t == 1023) total[0] = ps[1023];
}

// scatter guides to bucketed slots; entry = {id | class<<24, x+1 | y+1<<9 | z+1<<18}
__global__ void scat(const int* __restrict__ guide, int ng,
                     int* __restrict__ cursor, int2* __restrict__ sorted) {
    int i = blockIdx.x * blockDim.x + threadIdx.x;
    if (i >= ng) return;
    int4 q = ((const int4*)guide)[i];
    int c;
    int b = bucket_of(q, &c);
    int pos = atomicAdd(&cursor[b], 1);
    int2 e;
    e.x = i | (c << 24);
    e.y = (q.y + 1) | ((q.z + 1) << 9) | ((q.w + 1) << 18);
    sorted[pos] = e;
}

// ---- main: one wave per tile of 16 same-bucket guides (uniform class, spatially
// coherent). Probe lane=(slot 0..3, m 0..15), 2 rounds -> idx0/idx1 + ballots.
// GEMM: per admissible slot, A[16x64] gathered bf16, B from global bf16 wt,
// 4x mfma_f32_16x16x32_bf16. C layout: col(n)=lane&15, row(m)=quad*4+reg. ----
template<int USEFB>
__launch_bounds__(256, 4)
__global__ void gen_conv(const float* __restrict__ feats,        // [Np,64] fp32
                         const unsigned short* __restrict__ fb,  // [Np,64] bf16
                         const float* __restrict__ bias,         // [32]
                         const int* __restrict__ table,          // [2^21]
                         const int2* __restrict__ sorted,        // padded, w/ coords
                         const int* __restrict__ totalp,         // [1]
                         const unsigned short* __restrict__ wt,  // [27][32][64] bf16
                         float* __restrict__ out) {
    // bijective XCD swizzle: consecutive final tiles stay on one XCD's L2
    int nwg = gridDim.x;
    int orig = blockIdx.x;
    int qd = nwg >> 3, rd = nwg & 7;
    int xc = orig & 7, ix = orig >> 3;
    int wg = (xc < rd ? xc * (qd + 1) : rd * (qd + 1) + (xc - rd) * qd) + ix;

    int tile = wg * 4 + (threadIdx.x >> 6);
    int lane = threadIdx.x & 63;
    int m    = lane & 15;          // guide-row in tile / B n-col
    int quad = lane >> 4;          // k-octet / probe slot base

    int total = totalp[0];
    int t16 = tile * 16;
    if (t16 >= total) return;

    int2 s2 = sorted[t16 + m];
    // row 0 of every tile is always a valid entry -> class from lane 0
    int c = (__builtin_amdgcn_readfirstlane(s2.x) >> 24) & 7;
    int ex = c & 1, ey = (c >> 1) & 1, ez = (c >> 2) & 1;
    int id = s2.x < 0 ? -1 : (s2.x & 0xffffff);
    int qx = (s2.y & 511) - 1;
    int qy = ((s2.y >> 9) & 511) - 1;
    int qz = ((s2.y >> 18) & 511) - 1;

    // probe rounds: sub = quad (round0), quad+4 (round1)
    int idxr[2];
    #pragma unroll
    for (int r = 0; r < 2; ++r) {
        int sub = quad + r * 4;
        int offx = ex ? ((sub & 1) ? 1 : -1) : 0;
        int offy = ey ? ((sub & 2) ? 1 : -1) : 0;
        int offz = ez ? ((sub & 4) ? 1 : -1) : 0;
        int px = qx - offx, py = qy - offy, pz = qz - offz;
        bool valid = (id >= 0) & ((sub & ~c & 7) == 0) &
                     ((unsigned)px < 256u) & ((unsigned)py < 256u) & ((unsigned)pz < 256u);
        int lin = (px >> 1) | ((py >> 1) << 7) | ((pz >> 1) << 14);
        int v = table[valid ? lin : 0];
        idxr[r] = valid ? v : -1;
    }

    unsigned long long bal0 = __ballot(idxr[0] >= 0);
    unsigned long long bal1 = __ballot(idxr[1] >= 0);
    unsigned long long eb = bal0 | bal1;
    unsigned e16 = (unsigned)((eb | (eb >> 16) | (eb >> 32) | (eb >> 48)) & 0xffffull);

    float4v acc0 = {0.f, 0.f, 0.f, 0.f};
    float4v acc1 = {0.f, 0.f, 0.f, 0.f};

    #pragma unroll
    for (int sub = 0; sub < 8; ++sub) {
        if (sub & ~c & 7) continue;    // inadmissible for this class (uniform)
        unsigned long long bal = (sub < 4) ? bal0 : bal1;
        unsigned rowm = (unsigned)((bal >> ((sub & 3) * 16)) & 0xffffull);
        if (rowm == 0) continue;

        int srcl = (sub & 3) * 16 + m;
        int hidx = __shfl((sub < 4) ? idxr[0] : idxr[1], srcl, 64);

        // A fragments: row m, k = quad*8+j (a0: k<32, a1: k>=32)
        short8 a0 = {0,0,0,0,0,0,0,0};
        short8 a1 = {0,0,0,0,0,0,0,0};
        if (hidx >= 0) {
            if constexpr (USEFB) {
                const unsigned short* fp = fb + (size_t)hidx * NIN + quad * 8;
                a0 = *(const short8*)fp;
                a1 = *(const short8*)(fp + 32);
            } else {
                const float4* fp = (const float4*)(feats + (size_t)hidx * NIN + quad * 8);
                float4 fA = fp[0], fB = fp[1];
                const float4* fp2 = (const float4*)(feats + (size_t)hidx * NIN + 32 + quad * 8);
                float4 fC = fp2[0], fD = fp2[1];
                a0[0] = (short)bf16rne(fA.x); a0[1] = (short)bf16rne(fA.y);
                a0[2] = (short)bf16rne(fA.z); a0[3] = (short)bf16rne(fA.w);
                a0[4] = (short)bf16rne(fB.x); a0[5] = (short)bf16rne(fB.y);
                a0[6] = (short)bf16rne(fB.z); a0[7] = (short)bf16rne(fB.w);
                a1[0] = (short)bf16rne(fC.x); a1[1] = (short)bf16rne(fC.y);
                a1[2] = (short)bf16rne(fC.z); a1[3] = (short)bf16rne(fC.w);
                a1[4] = (short)bf16rne(fD.x); a1[5] = (short)bf16rne(fD.y);
                a1[6] = (short)bf16rne(fD.z); a1[7] = (short)bf16rne(fD.w);
            }
        }

        int offx = ex ? ((sub & 1) ? 1 : -1) : 0;
        int offy = ey ? ((sub & 2) ? 1 : -1) : 0;
        int offz = ez ? ((sub & 4) ? 1 : -1) : 0;
        int oi = (offx + 1) * 9 + (offy + 1) * 3 + (offz + 1);

        // B fragments: lane holds B[k=quad*8+j][n=m]; wt[oi][ch][k]
        const unsigned short* wb = wt + oi * 2048 + m * 64 + quad * 8;
        short8 b00 = *(const short8*)(wb);               // k<32,  ch m
        short8 b01 = *(const short8*)(wb + 1024);        // k<32,  ch 16+m
        short8 b10 = *(const short8*)(wb + 32);          // k>=32, ch m
        short8 b11 = *(const short8*)(wb + 1024 + 32);   // k>=32, ch 16+m

        acc0 = __builtin_amdgcn_mfma_f32_16x16x32_bf16(a0, b00, acc0, 0, 0, 0);
        acc0 = __builtin_amdgcn_mfma_f32_16x16x32_bf16(a1, b10, acc0, 0, 0, 0);
        acc1 = __builtin_amdgcn_mfma_f32_16x16x32_bf16(a0, b01, acc1, 0, 0, 0);
        acc1 = __builtin_amdgcn_mfma_f32_16x16x32_bf16(a1, b11, acc1, 0, 0, 0);
    }

    // store: lane's col n=m; rows mr=quad*4+r
    float bv0 = bias[m], bv1 = bias[16 + m];
    #pragma unroll
    for (int r = 0; r < 4; ++r) {
        int mr = quad * 4 + r;
        int idr = __shfl(id, mr, 64);      // lanes 0..15 hold the 16 ids
        if (idr >= 0) {
            bool exr = (e16 >> mr) & 1;
            float v0 = exr ? (acc0[r] + bv0) : 0.f;
            float v1 = exr ? (acc1[r] + bv1) : 0.f;
            out[(size_t)idr * NOUT + m]      = v0;
            out[(size_t)idr * NOUT + 16 + m] = v1;
        }
    }
}

extern "C" void kernel_launch(void* const* d_in, const int* in_sizes, int n_in,
                              void* d_out, int out_size, void* d_ws, size_t ws_size,
                              hipStream_t stream) {
    const float* feats   = (const float*)d_in[0];
    const float* weights = (const float*)d_in[1];
    const float* bias    = (const float*)d_in[2];
    const int*   coords  = (const int*)d_in[3];
    const int*   guide   = (const int*)d_in[4];
    float* out = (float*)d_out;

    int np = in_sizes[3] / 4;
    int ng = in_sizes[4] / 4;

    int* wsI = (int*)d_ws;
    int SC = (ng + NB * 16 + 3) & ~3;        // bucketed capacity (entries)
    int A = TSIZE + 2 * SC;                  // sorted is int2
    int* table   = wsI;                      // 2^21
    int2* sorted = (int2*)(wsI + TSIZE);     // SC entries, -1 padded
    int* count   = wsI + A;                  // NB
    int* cursor  = wsI + A + NB;             // NB
    int* total   = wsI + A + 2 * NB;         // 1 (+3 pad)
    unsigned short* wt = (unsigned short*)(wsI + A + 2 * NB + 4);   // 27*32*64 bf16
    unsigned short* fb = (unsigned short*)(wsI + A + 2 * NB + 4 + 27648);
    size_t need = ((size_t)A + 2 * NB + 4 + 27648) * 4 + (size_t)np * NIN * 2;
    int usefb = (ws_size >= need) ? 1 : 0;

    int n4 = A / 4;
    int fn4 = usefb ? np * (NIN / 4) : 0;
    int prep_n = n4 > fn4 ? n4 : fn4;
    if (prep_n < 27 * 64 * 32) prep_n = 27 * 64 * 32;
    hipLaunchKernelGGL(prep, dim3((prep_n + 255) / 256), dim3(256), 0, stream,
                       (int4*)wsI, n4, (int4*)count, weights, wt, feats, fb, fn4);

    int bc_n = np > ng ? np : ng;
    hipLaunchKernelGGL(bc, dim3((bc_n + 255) / 256), dim3(256), 0, stream,
                       coords, np, table, guide, ng, count);

    hipLaunchKernelGGL(scanB, dim3(1), dim3(1024), 0, stream, count, cursor, total);

    hipLaunchKernelGGL(scat, dim3((ng + 255) / 256), dim3(256), 0, stream,
                       guide, ng, cursor, sorted);

    int maxtiles = (ng + NB * 15 + 15) / 16;
    int blocks = (maxtiles + 3) / 4;         // 4 waves (tiles) per block
    if (usefb) {
        hipLaunchKernelGGL((gen_conv<1>), dim3(blocks), dim3(256), 0, stream,
                           feats, fb, bias, table, sorted, total, wt, out);
    } else {
        hipLaunchKernelGGL((gen_conv<0>), dim3(blocks), dim3(256), 0, stream,
                           feats, fb, bias, table, sorted, total, wt, out);
    }
}